// Round 2
// baseline (203.443 us; speedup 1.0000x reference)
//
#include <hip/hip_runtime.h>
#include <hip/hip_bf16.h>

typedef unsigned short u16;
typedef __bf16 bf16x8 __attribute__((ext_vector_type(8)));
typedef float f32x4 __attribute__((ext_vector_type(4)));
typedef float f32x16 __attribute__((ext_vector_type(16)));
typedef unsigned u32x2 __attribute__((ext_vector_type(2)));
typedef unsigned u32x4 __attribute__((ext_vector_type(4)));

#define HIDDEN 1024
#define NH 16
#define HD 64
#define BATCH 2
#define SEQ 2048
#define MTOT (BATCH*SEQ)   // 4096
#define CEXP 0.18033688f   // 0.125 * log2(e), folded into Q at projection time
#define KVB 128            // K/V tile (t) per iteration

#if __has_builtin(__builtin_amdgcn_exp2f)
#define EXP2(x) __builtin_amdgcn_exp2f(x)
#else
#define EXP2(x) __builtin_exp2f(x)
#endif

__device__ __forceinline__ u16 f2bf(float f) {
  union { float f; unsigned u; } v; v.f = f;
  unsigned u = v.u;
  return (u16)((u + 0x7fffu + ((u >> 16) & 1u)) >> 16);   // RNE
}

__device__ __forceinline__ unsigned pack2bf(float a, float b) {
  __hip_bfloat162 h = __float22bfloat162_rn(make_float2(a, b));
  unsigned u; __builtin_memcpy(&u, &h, 4); return u;
}

__device__ __forceinline__ void gload16(const u16* g, u16* l) {
  __builtin_amdgcn_global_load_lds((const __attribute__((address_space(1))) unsigned int*)g,
                                   (__attribute__((address_space(3))) unsigned int*)l, 16, 0, 0);
}

// ---------------- prep: x fp32 -> bf16 ----------------
__global__ __launch_bounds__(256) void convert_x_kernel(const float* __restrict__ x,
                                                        u16* __restrict__ xb) {
  size_t i = ((size_t)blockIdx.x * 256 + threadIdx.x) * 4;
  float4 v = *(const float4*)(x + i);
  uint2 p;
  p.x = pack2bf(v.x, v.y);
  p.y = pack2bf(v.z, v.w);
  *(uint2*)(xb + i) = p;
}

// ---------------- prep: W (k,n) fp32 -> Wt (n,k) bf16 ----------------
__global__ __launch_bounds__(256) void transpose_w_kernel(const float* __restrict__ w0, const float* __restrict__ w1,
                                                          const float* __restrict__ w2, const float* __restrict__ w3,
                                                          u16* __restrict__ dqkv, u16* __restrict__ dwo) {
  __shared__ float t[32][33];
  int z = blockIdx.z;
  const float* src = (z==0) ? w0 : (z==1) ? w1 : (z==2) ? w2 : w3;
  u16* dst = (z < 3) ? (dqkv + (size_t)z * HIDDEN * HIDDEN) : dwo;
  int kb = blockIdx.x * 32, nb = blockIdx.y * 32;
  int tx = threadIdx.x & 31, ty = threadIdx.x >> 5;
  for (int r = ty; r < 32; r += 8) t[r][tx] = src[(size_t)(kb + r) * HIDDEN + nb + tx];
  __syncthreads();
  for (int r = ty; r < 32; r += 8) dst[(size_t)(nb + r) * HIDDEN + kb + tx] = f2bf(t[tx][r]);
}

// ---------------- bf16 GEMM: C[m,n] = sum_k A[m,k]*Bt[n,k] + bias ----------------
// MT x 128 tile (MT=128 or 64), BK=32, global_load_lds width-16 staging.
// MODE 0: fp32 out = acc + b0[n]                       (output projection)
// MODE 1: bf16 out, 3 segments: Q (scaled by CEXP) -> Cq, K -> Cq,
//         V -> written TRANSPOSED per head into Cv[(bh*64+d)*SEQ + t]
//         (folds the old transpose_v kernel into the epilogue; 4 consecutive
//          t per thread -> one 8B store, replacing 4 scalar strided stores)
template<int MODE, int MT>
__global__ __launch_bounds__(256) void gemm_bt(const u16* __restrict__ A, const u16* __restrict__ Bt,
                                               const float* __restrict__ b0, const float* __restrict__ b1,
                                               const float* __restrict__ b2,
                                               u16* __restrict__ Cq, u16* __restrict__ Cv,
                                               float* __restrict__ Cf,
                                               int M, int N, int K) {
  constexpr int MF = MT / 32;           // m-frags per wave: 4 (MT=128) or 2 (MT=64)
  __shared__ u16 As[MT*32];
  __shared__ u16 Bs[128*32];
  const int tid = threadIdx.x, lane = tid & 63, wv = tid >> 6;
  const int m0 = blockIdx.x * MT, n0 = blockIdx.y * 128;
  const int wm = (wv >> 1) * (MT/2), wn = (wv & 1) * 64;
  const int col = lane & 15, quad = lane >> 4;
  const int lr = lane >> 2, lk = (lane & 3) * 8;
  f32x4 acc[MF][4] = {};
  for (int k0 = 0; k0 < K; k0 += 32) {
    if constexpr (MT == 128) {
      gload16(&A[(size_t)(m0 + wv*32      + lr)*K + k0 + lk], &As[wv*1024]);
      gload16(&A[(size_t)(m0 + wv*32 + 16 + lr)*K + k0 + lk], &As[wv*1024 + 512]);
    } else {
      gload16(&A[(size_t)(m0 + wv*16      + lr)*K + k0 + lk], &As[wv*512]);
    }
    gload16(&Bt[(size_t)(n0 + wv*32      + lr)*K + k0 + lk], &Bs[wv*1024]);
    gload16(&Bt[(size_t)(n0 + wv*32 + 16 + lr)*K + k0 + lk], &Bs[wv*1024 + 512]);
    __syncthreads();
    bf16x8 af[MF], bfr[4];
    #pragma unroll
    for (int i = 0; i < MF; i++) af[i]  = *(const bf16x8*)&As[(wm + i*16 + col)*32 + quad*8];
    #pragma unroll
    for (int i = 0; i < 4; i++)  bfr[i] = *(const bf16x8*)&Bs[(wn + i*16 + col)*32 + quad*8];
    #pragma unroll
    for (int mi = 0; mi < MF; mi++)
      #pragma unroll
      for (int ni = 0; ni < 4; ni++)
        acc[mi][ni] = __builtin_amdgcn_mfma_f32_16x16x32_bf16(af[mi], bfr[ni], acc[mi][ni], 0, 0, 0);
    __syncthreads();
  }
  if constexpr (MODE == 0) {
    #pragma unroll
    for (int mi = 0; mi < MF; mi++)
      #pragma unroll
      for (int ni = 0; ni < 4; ni++) {
        int n = n0 + wn + ni*16 + col;
        float bias = b0[n];
        #pragma unroll
        for (int r = 0; r < 4; r++) {
          int m = m0 + wm + mi*16 + quad*4 + r;   // C/D: row = quad*4+reg, col = lane&15
          Cf[(size_t)m*N + n] = acc[mi][ni][r] + bias;
        }
      }
  } else {
    const int seg = n0 >> 10;   // 0=Q, 1=K, 2=V
    if (seg < 2) {
      const float* bias = (seg == 0) ? b0 : b1;
      const float scl = (seg == 0) ? CEXP : 1.0f;
      #pragma unroll
      for (int mi = 0; mi < MF; mi++)
        #pragma unroll
        for (int ni = 0; ni < 4; ni++) {
          int n = n0 + wn + ni*16 + col;
          float bv = bias[n & (HIDDEN-1)];
          #pragma unroll
          for (int r = 0; r < 4; r++) {
            int m = m0 + wm + mi*16 + quad*4 + r;
            Cq[(size_t)m*N + n] = f2bf((acc[mi][ni][r] + bv) * scl);
          }
        }
    } else {
      // V segment: transpose-on-store. n -> (h,d); m -> (b,t); vt[(b*16+h)*64+d][t]
      const int bb = m0 >> 11;             // 2048 % 128 == 0: block never straddles b
      #pragma unroll
      for (int mi = 0; mi < MF; mi++)
        #pragma unroll
        for (int ni = 0; ni < 4; ni++) {
          int local = (n0 + wn + ni*16 + col) & (HIDDEN-1);
          int hh = local >> 6, dd = local & 63;
          float bv = b2[local];
          int t4 = (m0 + wm + mi*16 + quad*4) & (SEQ-1);
          uint2 w2;
          w2.x = pack2bf(acc[mi][ni][0] + bv, acc[mi][ni][1] + bv);
          w2.y = pack2bf(acc[mi][ni][2] + bv, acc[mi][ni][3] + bv);
          *(uint2*)&Cv[((size_t)((bb*NH + hh)*HD + dd))*SEQ + t4] = w2;
        }
    }
  }
}

// ---------------- flash attention, 32x32 MFMA, fully in-register P ----------------
// block: 128 q of one (b,h); 4 waves x 32 q. KVB=128 t per iter, double-buffered
// K/V LDS, ONE barrier/iter (16 iters). S^T = K Q^T (A=K, B=Q): col=q=lane&31,
// rows t=(reg&3)+8*(reg>>2)+4*(lane>>5). PV B-frag has the same lane->q mapping,
// so P redistribution is cvt_pk pairs + permlane32_swap only (no LDS round-trip).
// Row sums: f32 VALU accumulation fused into the exp2 loop (each lane's 32
// t-slots per tt union with its half-partner's to cover all t for q=lane&31),
// one cross-half shfl_xor(32) at the end. No ones-MFMA.
__global__ __launch_bounds__(256) void attn_kernel(const u16* __restrict__ qkv,
                                                   const u16* __restrict__ vt,
                                                   u16* __restrict__ ao) {
  __shared__ u16 Ks[2*KVB*72];     // [buf][t][d], stride 72   (36864 B)
  __shared__ u16 Vs[2*64*136];     // [buf][d][t], stride 136  (34816 B)
  const int tid = threadIdx.x, lane = tid & 63, wv = tid >> 6;
  const int qt = blockIdx.x, bh = blockIdx.y;
  const int b = bh >> 4, h = bh & 15;
  const int l31 = lane & 31, hl = lane >> 5;

  // Q as 32x32x16 B-frags: n=q=l31, elem j at d = kk*16 + hl*8 + j
  bf16x8 qf[4];
  {
    const u16* qrow = qkv + (size_t)(b*SEQ + qt*128 + wv*32 + l31)*(3*HIDDEN) + h*HD + hl*8;
    #pragma unroll
    for (int kk = 0; kk < 4; kk++) qf[kk] = *(const bf16x8*)(qrow + kk*16);
  }

  f32x16 o[2] = {};        // O^T acc [mt]: col=q, rows d = mt*32 + (reg&3)+8*(reg>>2)+4*hl
  float rs0 = 0.f, rs1 = 0.f;   // two independent row-sum chains

  // K staging: 128 rows (t) x 64 d; 32 rows per step, 4 steps
  const int rK = tid >> 3, koK = (tid & 7) * 8;
  // V staging: 64 rows (d) x 128 t; 16 rows per step, 4 steps
  const int rV = tid >> 4, koV = (tid & 15) * 8;
  const u16* gK = qkv + (size_t)b*SEQ*(3*HIDDEN) + HIDDEN + (size_t)h*HD;   // row stride 3072
  const u16* gV = vt + (size_t)bh*HD*SEQ;                                    // row stride 2048
  uint4 pK[4], pV[4];
  #pragma unroll
  for (int s4 = 0; s4 < 4; s4++) {
    pK[s4] = *(const uint4*)&gK[(size_t)(rK + 32*s4)*(3*HIDDEN) + koK];
    pV[s4] = *(const uint4*)&gV[(size_t)(rV + 16*s4)*SEQ + koV];
  }

  for (int it = 0; it < SEQ/KVB; ++it) {
    const int curK = (it & 1) * (KVB*72);
    const int curV = (it & 1) * (64*136);
    #pragma unroll
    for (int s4 = 0; s4 < 4; s4++) {
      *(uint4*)&Ks[curK + (rK + 32*s4)*72 + koK] = pK[s4];
      *(uint4*)&Vs[curV + (rV + 16*s4)*136 + koV] = pV[s4];
    }
    __syncthreads();   // tile visible; other waves at most touch the other buffer
    if (it < SEQ/KVB - 1) {   // prefetch after barrier: loads fly during compute
      int t0 = (it + 1) * KVB;
      #pragma unroll
      for (int s4 = 0; s4 < 4; s4++) {
        pK[s4] = *(const uint4*)&gK[(size_t)(t0 + rK + 32*s4)*(3*HIDDEN) + koK];
        pV[s4] = *(const uint4*)&gV[(size_t)(rV + 16*s4)*SEQ + t0 + koV];
      }
    }

    // S^T = K Q^T: four 32x32 t-subtiles, 4 k-steps of 16 over d (16 MFMA, 4 chains)
    f32x16 sc[4] = {};
    #pragma unroll
    for (int kk = 0; kk < 4; kk++)
      #pragma unroll
      for (int tt = 0; tt < 4; tt++) {
        bf16x8 kf = *(const bf16x8*)&Ks[curK + (tt*32 + l31)*72 + kk*16 + hl*8];
        sc[tt] = __builtin_amdgcn_mfma_f32_32x32x16_bf16(kf, qf[kk], sc[tt], 0, 0, 0);
      }

    // per t-subtile: exp2 + rowsum -> packed bf16 -> permlane -> PV MFMAs
    #pragma unroll
    for (int tt = 0; tt < 4; tt++) {
      unsigned w[8];
      #pragma unroll
      for (int j = 0; j < 8; j++) {
        float p0 = EXP2(sc[tt][2*j]);
        float p1 = EXP2(sc[tt][2*j+1]);
        rs0 += p0; rs1 += p1;
        w[j] = pack2bf(p0, p1);      // t-pair {8*(j>>1)+2*(j&1)+4*hl, +1} within chunk
      }
      // exchange reg-halves across lane<32 / lane>=32 (one swap fills two words)
      u32x2 r02 = __builtin_amdgcn_permlane32_swap(w[0], w[2], false, false);
      u32x2 r13 = __builtin_amdgcn_permlane32_swap(w[1], w[3], false, false);
      u32x2 r46 = __builtin_amdgcn_permlane32_swap(w[4], w[6], false, false);
      u32x2 r57 = __builtin_amdgcn_permlane32_swap(w[5], w[7], false, false);
      u32x4 c0, c1;
      c0.x = r02[0]; c0.y = r13[0]; c0.z = r02[1]; c0.w = r13[1];   // t-chunk tt*32 + 0..15
      c1.x = r46[0]; c1.y = r57[0]; c1.z = r46[1]; c1.w = r57[1];   // t-chunk tt*32 + 16..31
      bf16x8 pf0 = __builtin_bit_cast(bf16x8, c0);
      bf16x8 pf1 = __builtin_bit_cast(bf16x8, c1);

      #pragma unroll
      for (int mt = 0; mt < 2; mt++) {
        bf16x8 vf0 = *(const bf16x8*)&Vs[curV + (mt*32 + l31)*136 + tt*32 + hl*8];
        bf16x8 vf1 = *(const bf16x8*)&Vs[curV + (mt*32 + l31)*136 + tt*32 + 16 + hl*8];
        o[mt] = __builtin_amdgcn_mfma_f32_32x32x16_bf16(vf0, pf0, o[mt], 0, 0, 0);
        o[mt] = __builtin_amdgcn_mfma_f32_32x32x16_bf16(vf1, pf1, o[mt], 0, 0, 0);
      }
    }
  }

  // row sum: lane's own t-subset + half-partner's subset covers all t for q=l31
  float my = rs0 + rs1;
  float inv = 1.0f / (my + __shfl_xor(my, 32, 64));

  // store O^T -> ao[q][h*64+d]; lane's column q = l31 fixed
  u16* aop = ao + (size_t)(b*SEQ + qt*128 + wv*32 + l31)*HIDDEN + h*HD + hl*4;
  #pragma unroll
  for (int mt = 0; mt < 2; mt++)
    #pragma unroll
    for (int a4 = 0; a4 < 4; a4++) {
      uint2 w2;
      w2.x = pack2bf(o[mt][4*a4+0]*inv, o[mt][4*a4+1]*inv);
      w2.y = pack2bf(o[mt][4*a4+2]*inv, o[mt][4*a4+3]*inv);
      *(uint2*)&aop[mt*32 + 8*a4] = w2;
    }
}

extern "C" void kernel_launch(void* const* d_in, const int* in_sizes, int n_in,
                              void* d_out, int out_size, void* d_ws, size_t ws_size,
                              hipStream_t stream) {
  const float* x  = (const float*)d_in[0];
  const float* Wq = (const float*)d_in[1];
  const float* bq = (const float*)d_in[2];
  const float* Wk = (const float*)d_in[3];
  const float* bk = (const float*)d_in[4];
  const float* Wv = (const float*)d_in[5];
  const float* bv = (const float*)d_in[6];
  const float* Wo = (const float*)d_in[7];
  const float* bo = (const float*)d_in[8];
  float* out = (float*)d_out;

  char* w = (char*)d_ws;
  u16* xb    = (u16*)w; w += (size_t)MTOT*HIDDEN*2;        // 8 MB
  u16* wtqkv = (u16*)w; w += (size_t)3*HIDDEN*HIDDEN*2;    // 6 MB
  u16* wto   = (u16*)w; w += (size_t)HIDDEN*HIDDEN*2;      // 2 MB
  u16* qkvb  = (u16*)w; w += (size_t)MTOT*3*HIDDEN*2;      // 24 MB (V seg unused)
  u16* vtb   = (u16*)w; w += (size_t)BATCH*NH*HD*SEQ*2;    // 8 MB
  u16* aob   = (u16*)w; w += (size_t)MTOT*HIDDEN*2;        // 8 MB

  convert_x_kernel<<<(MTOT*HIDDEN)/1024, 256, 0, stream>>>(x, xb);
  transpose_w_kernel<<<dim3(32, 32, 4), 256, 0, stream>>>(Wq, Wk, Wv, Wo, wtqkv, wto);
  gemm_bt<1,128><<<dim3(32, 24), 256, 0, stream>>>(xb, wtqkv, bq, bk, bv, qkvb, vtb, nullptr, MTOT, 3*HIDDEN, HIDDEN);
  attn_kernel<<<dim3(SEQ/128, BATCH*NH), 256, 0, stream>>>(qkvb, vtb, aob);
  gemm_bt<0,64><<<dim3(64, 8), 256, 0, stream>>>(aob, wto, bo, nullptr, nullptr, nullptr, nullptr, out, MTOT, HIDDEN, HIDDEN);
}

// Round 3
// 177.898 us; speedup vs baseline: 1.1436x; 1.1436x over previous
//
#include <hip/hip_runtime.h>
#include <hip/hip_bf16.h>

typedef unsigned short u16;
typedef __bf16 bf16x8 __attribute__((ext_vector_type(8)));
typedef float f32x4 __attribute__((ext_vector_type(4)));
typedef float f32x16 __attribute__((ext_vector_type(16)));
typedef unsigned u32x2 __attribute__((ext_vector_type(2)));
typedef unsigned u32x4 __attribute__((ext_vector_type(4)));

#define HIDDEN 1024
#define NH 16
#define HD 64
#define BATCH 2
#define SEQ 2048
#define MTOT (BATCH*SEQ)   // 4096
#define CEXP 0.18033688f   // 0.125 * log2(e), folded into Q at projection time
#define KVB 128            // K/V tile (t) per iteration

#if __has_builtin(__builtin_amdgcn_exp2f)
#define EXP2(x) __builtin_amdgcn_exp2f(x)
#else
#define EXP2(x) __builtin_exp2f(x)
#endif

__device__ __forceinline__ u16 f2bf(float f) {
  union { float f; unsigned u; } v; v.f = f;
  unsigned u = v.u;
  return (u16)((u + 0x7fffu + ((u >> 16) & 1u)) >> 16);   // RNE
}

__device__ __forceinline__ unsigned pack2bf(float a, float b) {
  __hip_bfloat162 h = __float22bfloat162_rn(make_float2(a, b));
  unsigned u; __builtin_memcpy(&u, &h, 4); return u;
}

__device__ __forceinline__ void gload16(const u16* g, u16* l) {
  __builtin_amdgcn_global_load_lds((const __attribute__((address_space(1))) unsigned int*)g,
                                   (__attribute__((address_space(3))) unsigned int*)l, 16, 0, 0);
}

// ---------------- prep: x fp32 -> bf16 ----------------
__global__ __launch_bounds__(256) void convert_x_kernel(const float* __restrict__ x,
                                                        u16* __restrict__ xb) {
  size_t i = ((size_t)blockIdx.x * 256 + threadIdx.x) * 4;
  float4 v = *(const float4*)(x + i);
  uint2 p;
  p.x = pack2bf(v.x, v.y);
  p.y = pack2bf(v.z, v.w);
  *(uint2*)(xb + i) = p;
}

// ---------------- prep: W (k,n) fp32 -> Wt (n,k) bf16 ----------------
__global__ __launch_bounds__(256) void transpose_w_kernel(const float* __restrict__ w0, const float* __restrict__ w1,
                                                          const float* __restrict__ w2, const float* __restrict__ w3,
                                                          u16* __restrict__ dqkv, u16* __restrict__ dwo) {
  __shared__ float t[32][33];
  int z = blockIdx.z;
  const float* src = (z==0) ? w0 : (z==1) ? w1 : (z==2) ? w2 : w3;
  u16* dst = (z < 3) ? (dqkv + (size_t)z * HIDDEN * HIDDEN) : dwo;
  int kb = blockIdx.x * 32, nb = blockIdx.y * 32;
  int tx = threadIdx.x & 31, ty = threadIdx.x >> 5;
  for (int r = ty; r < 32; r += 8) t[r][tx] = src[(size_t)(kb + r) * HIDDEN + nb + tx];
  __syncthreads();
  for (int r = ty; r < 32; r += 8) dst[(size_t)(nb + r) * HIDDEN + kb + tx] = f2bf(t[tx][r]);
}

// ---------------- bf16 GEMM: C[m,n] = sum_k A[m,k]*Bt[n,k] + bias ----------------
// MT x 128 tile (MT=128 or 64), BK=32, global_load_lds width-16 staging.
// MODE 0: fp32 out = acc + b0[n]                       (output projection)
// MODE 1: bf16 out, 3 segments: Q (scaled by CEXP) -> Cq, K -> Cq,
//         V -> written TRANSPOSED per head into Cv[(bh*64+d)*SEQ + t]
template<int MODE, int MT>
__global__ __launch_bounds__(256) void gemm_bt(const u16* __restrict__ A, const u16* __restrict__ Bt,
                                               const float* __restrict__ b0, const float* __restrict__ b1,
                                               const float* __restrict__ b2,
                                               u16* __restrict__ Cq, u16* __restrict__ Cv,
                                               float* __restrict__ Cf,
                                               int M, int N, int K) {
  constexpr int MF = MT / 32;           // m-frags per wave: 4 (MT=128) or 2 (MT=64)
  __shared__ u16 As[MT*32];
  __shared__ u16 Bs[128*32];
  const int tid = threadIdx.x, lane = tid & 63, wv = tid >> 6;
  const int m0 = blockIdx.x * MT, n0 = blockIdx.y * 128;
  const int wm = (wv >> 1) * (MT/2), wn = (wv & 1) * 64;
  const int col = lane & 15, quad = lane >> 4;
  const int lr = lane >> 2, lk = (lane & 3) * 8;
  f32x4 acc[MF][4] = {};
  for (int k0 = 0; k0 < K; k0 += 32) {
    if constexpr (MT == 128) {
      gload16(&A[(size_t)(m0 + wv*32      + lr)*K + k0 + lk], &As[wv*1024]);
      gload16(&A[(size_t)(m0 + wv*32 + 16 + lr)*K + k0 + lk], &As[wv*1024 + 512]);
    } else {
      gload16(&A[(size_t)(m0 + wv*16      + lr)*K + k0 + lk], &As[wv*512]);
    }
    gload16(&Bt[(size_t)(n0 + wv*32      + lr)*K + k0 + lk], &Bs[wv*1024]);
    gload16(&Bt[(size_t)(n0 + wv*32 + 16 + lr)*K + k0 + lk], &Bs[wv*1024 + 512]);
    __syncthreads();
    bf16x8 af[MF], bfr[4];
    #pragma unroll
    for (int i = 0; i < MF; i++) af[i]  = *(const bf16x8*)&As[(wm + i*16 + col)*32 + quad*8];
    #pragma unroll
    for (int i = 0; i < 4; i++)  bfr[i] = *(const bf16x8*)&Bs[(wn + i*16 + col)*32 + quad*8];
    #pragma unroll
    for (int mi = 0; mi < MF; mi++)
      #pragma unroll
      for (int ni = 0; ni < 4; ni++)
        acc[mi][ni] = __builtin_amdgcn_mfma_f32_16x16x32_bf16(af[mi], bfr[ni], acc[mi][ni], 0, 0, 0);
    __syncthreads();
  }
  if constexpr (MODE == 0) {
    #pragma unroll
    for (int mi = 0; mi < MF; mi++)
      #pragma unroll
      for (int ni = 0; ni < 4; ni++) {
        int n = n0 + wn + ni*16 + col;
        float bias = b0[n];
        #pragma unroll
        for (int r = 0; r < 4; r++) {
          int m = m0 + wm + mi*16 + quad*4 + r;   // C/D: row = quad*4+reg, col = lane&15
          Cf[(size_t)m*N + n] = acc[mi][ni][r] + bias;
        }
      }
  } else {
    const int seg = n0 >> 10;   // 0=Q, 1=K, 2=V
    if (seg < 2) {
      const float* bias = (seg == 0) ? b0 : b1;
      const float scl = (seg == 0) ? CEXP : 1.0f;
      #pragma unroll
      for (int mi = 0; mi < MF; mi++)
        #pragma unroll
        for (int ni = 0; ni < 4; ni++) {
          int n = n0 + wn + ni*16 + col;
          float bv = bias[n & (HIDDEN-1)];
          #pragma unroll
          for (int r = 0; r < 4; r++) {
            int m = m0 + wm + mi*16 + quad*4 + r;
            Cq[(size_t)m*N + n] = f2bf((acc[mi][ni][r] + bv) * scl);
          }
        }
    } else {
      // V segment: transpose-on-store. n -> (h,d); m -> (b,t); vt[(b*16+h)*64+d][t]
      const int bb = m0 >> 11;             // 2048 % 128 == 0: block never straddles b
      #pragma unroll
      for (int mi = 0; mi < MF; mi++)
        #pragma unroll
        for (int ni = 0; ni < 4; ni++) {
          int local = (n0 + wn + ni*16 + col) & (HIDDEN-1);
          int hh = local >> 6, dd = local & 63;
          float bv = b2[local];
          int t4 = (m0 + wm + mi*16 + quad*4) & (SEQ-1);
          uint2 w2;
          w2.x = pack2bf(acc[mi][ni][0] + bv, acc[mi][ni][1] + bv);
          w2.y = pack2bf(acc[mi][ni][2] + bv, acc[mi][ni][3] + bv);
          *(uint2*)&Cv[((size_t)((bb*NH + hh)*HD + dd))*SEQ + t4] = w2;
        }
    }
  }
}

// ---------------- flash attention, 32x32 MFMA, fully in-register P ----------------
// block: 128 q of one (b,h); 4 waves x 32 q. KVB=128 t per iter, double-buffered
// K/V LDS, ONE barrier/iter (16 iters). S^T = K Q^T (A=K, B=Q): col=q=lane&31,
// rows t=(reg&3)+8*(reg>>2)+4*(lane>>5). PV B-frag has the same lane->q mapping,
// so P redistribution is cvt_pk pairs + permlane32_swap only (no LDS round-trip).
// t-subtiles processed in PAIRS (QK pair -> softmax+PV pair) so only 2 f32x16
// S-accumulators are live at once; __launch_bounds__(256,2) gives the allocator
// the true 2-waves/SIMD budget (256 VGPR) -- R2's spill (252 MB scratch writes,
// VGPR pinned at 96) came from 4 live S-accs under a default-occupancy budget.
__global__ __launch_bounds__(256, 2) void attn_kernel(const u16* __restrict__ qkv,
                                                      const u16* __restrict__ vt,
                                                      u16* __restrict__ ao) {
  __shared__ u16 Ks[2*KVB*72];     // [buf][t][d], stride 72   (36864 B)
  __shared__ u16 Vs[2*64*136];     // [buf][d][t], stride 136  (34816 B)
  const int tid = threadIdx.x, lane = tid & 63, wv = tid >> 6;
  const int qt = blockIdx.x, bh = blockIdx.y;
  const int b = bh >> 4, h = bh & 15;
  const int l31 = lane & 31, hl = lane >> 5;

  // Q as 32x32x16 B-frags: n=q=l31, elem j at d = kk*16 + hl*8 + j
  bf16x8 qf[4];
  {
    const u16* qrow = qkv + (size_t)(b*SEQ + qt*128 + wv*32 + l31)*(3*HIDDEN) + h*HD + hl*8;
    #pragma unroll
    for (int kk = 0; kk < 4; kk++) qf[kk] = *(const bf16x8*)(qrow + kk*16);
  }

  f32x16 o[2] = {};        // O^T acc [mt]: col=q, rows d = mt*32 + (reg&3)+8*(reg>>2)+4*hl
  float rs0 = 0.f, rs1 = 0.f;   // two independent row-sum chains

  // K staging: 128 rows (t) x 64 d; 32 rows per step, 4 steps
  const int rK = tid >> 3, koK = (tid & 7) * 8;
  // V staging: 64 rows (d) x 128 t; 16 rows per step, 4 steps
  const int rV = tid >> 4, koV = (tid & 15) * 8;
  const u16* gK = qkv + (size_t)b*SEQ*(3*HIDDEN) + HIDDEN + (size_t)h*HD;   // row stride 3072
  const u16* gV = vt + (size_t)bh*HD*SEQ;                                    // row stride 2048
  uint4 pK[4], pV[4];
  #pragma unroll
  for (int s4 = 0; s4 < 4; s4++) {
    pK[s4] = *(const uint4*)&gK[(size_t)(rK + 32*s4)*(3*HIDDEN) + koK];
    pV[s4] = *(const uint4*)&gV[(size_t)(rV + 16*s4)*SEQ + koV];
  }

  for (int it = 0; it < SEQ/KVB; ++it) {
    const int curK = (it & 1) * (KVB*72);
    const int curV = (it & 1) * (64*136);
    #pragma unroll
    for (int s4 = 0; s4 < 4; s4++) {
      *(uint4*)&Ks[curK + (rK + 32*s4)*72 + koK] = pK[s4];
      *(uint4*)&Vs[curV + (rV + 16*s4)*136 + koV] = pV[s4];
    }
    __syncthreads();   // tile visible; other waves at most touch the other buffer
    if (it < SEQ/KVB - 1) {   // prefetch after barrier: loads fly during compute
      int t0 = (it + 1) * KVB;
      #pragma unroll
      for (int s4 = 0; s4 < 4; s4++) {
        pK[s4] = *(const uint4*)&gK[(size_t)(t0 + rK + 32*s4)*(3*HIDDEN) + koK];
        pV[s4] = *(const uint4*)&gV[(size_t)(rV + 16*s4)*SEQ + t0 + koV];
      }
    }

    // t-subtile PAIRS: QK (2 chains) -> softmax+PV, then next pair.
    // PV of pair 0 is independent of QK of pair 1 -> scheduler overlap.
    #pragma unroll
    for (int tp = 0; tp < 2; tp++) {
      f32x16 sc[2] = {};
      __builtin_amdgcn_s_setprio(1);
      #pragma unroll
      for (int kk = 0; kk < 4; kk++)
        #pragma unroll
        for (int t2 = 0; t2 < 2; t2++) {
          const int tt = tp*2 + t2;
          bf16x8 kf = *(const bf16x8*)&Ks[curK + (tt*32 + l31)*72 + kk*16 + hl*8];
          sc[t2] = __builtin_amdgcn_mfma_f32_32x32x16_bf16(kf, qf[kk], sc[t2], 0, 0, 0);
        }
      __builtin_amdgcn_s_setprio(0);

      #pragma unroll
      for (int t2 = 0; t2 < 2; t2++) {
        const int tt = tp*2 + t2;
        unsigned w[8];
        #pragma unroll
        for (int j = 0; j < 8; j++) {
          float p0 = EXP2(sc[t2][2*j]);
          float p1 = EXP2(sc[t2][2*j+1]);
          rs0 += p0; rs1 += p1;
          w[j] = pack2bf(p0, p1);      // t-pair {8*(j>>1)+2*(j&1)+4*hl, +1} within chunk
        }
        // exchange reg-halves across lane<32 / lane>=32 (one swap fills two words)
        u32x2 r02 = __builtin_amdgcn_permlane32_swap(w[0], w[2], false, false);
        u32x2 r13 = __builtin_amdgcn_permlane32_swap(w[1], w[3], false, false);
        u32x2 r46 = __builtin_amdgcn_permlane32_swap(w[4], w[6], false, false);
        u32x2 r57 = __builtin_amdgcn_permlane32_swap(w[5], w[7], false, false);
        u32x4 c0, c1;
        c0.x = r02[0]; c0.y = r13[0]; c0.z = r02[1]; c0.w = r13[1];   // t-chunk tt*32 + 0..15
        c1.x = r46[0]; c1.y = r57[0]; c1.z = r46[1]; c1.w = r57[1];   // t-chunk tt*32 + 16..31
        bf16x8 pf0 = __builtin_bit_cast(bf16x8, c0);
        bf16x8 pf1 = __builtin_bit_cast(bf16x8, c1);

        __builtin_amdgcn_s_setprio(1);
        #pragma unroll
        for (int mt = 0; mt < 2; mt++) {
          bf16x8 vf0 = *(const bf16x8*)&Vs[curV + (mt*32 + l31)*136 + tt*32 + hl*8];
          bf16x8 vf1 = *(const bf16x8*)&Vs[curV + (mt*32 + l31)*136 + tt*32 + 16 + hl*8];
          o[mt] = __builtin_amdgcn_mfma_f32_32x32x16_bf16(vf0, pf0, o[mt], 0, 0, 0);
          o[mt] = __builtin_amdgcn_mfma_f32_32x32x16_bf16(vf1, pf1, o[mt], 0, 0, 0);
        }
        __builtin_amdgcn_s_setprio(0);
      }
    }
  }

  // row sum: lane's own t-subset + half-partner's subset covers all t for q=l31
  float my = rs0 + rs1;
  float inv = 1.0f / (my + __shfl_xor(my, 32, 64));

  // store O^T -> ao[q][h*64+d]; lane's column q = l31 fixed
  u16* aop = ao + (size_t)(b*SEQ + qt*128 + wv*32 + l31)*HIDDEN + h*HD + hl*4;
  #pragma unroll
  for (int mt = 0; mt < 2; mt++)
    #pragma unroll
    for (int a4 = 0; a4 < 4; a4++) {
      uint2 w2;
      w2.x = pack2bf(o[mt][4*a4+0]*inv, o[mt][4*a4+1]*inv);
      w2.y = pack2bf(o[mt][4*a4+2]*inv, o[mt][4*a4+3]*inv);
      *(uint2*)&aop[mt*32 + 8*a4] = w2;
    }
}

extern "C" void kernel_launch(void* const* d_in, const int* in_sizes, int n_in,
                              void* d_out, int out_size, void* d_ws, size_t ws_size,
                              hipStream_t stream) {
  const float* x  = (const float*)d_in[0];
  const float* Wq = (const float*)d_in[1];
  const float* bq = (const float*)d_in[2];
  const float* Wk = (const float*)d_in[3];
  const float* bk = (const float*)d_in[4];
  const float* Wv = (const float*)d_in[5];
  const float* bv = (const float*)d_in[6];
  const float* Wo = (const float*)d_in[7];
  const float* bo = (const float*)d_in[8];
  float* out = (float*)d_out;

  char* w = (char*)d_ws;
  u16* xb    = (u16*)w; w += (size_t)MTOT*HIDDEN*2;        // 8 MB
  u16* wtqkv = (u16*)w; w += (size_t)3*HIDDEN*HIDDEN*2;    // 6 MB
  u16* wto   = (u16*)w; w += (size_t)HIDDEN*HIDDEN*2;      // 2 MB
  u16* qkvb  = (u16*)w; w += (size_t)MTOT*3*HIDDEN*2;      // 24 MB (V seg unused)
  u16* vtb   = (u16*)w; w += (size_t)BATCH*NH*HD*SEQ*2;    // 8 MB
  u16* aob   = (u16*)w; w += (size_t)MTOT*HIDDEN*2;        // 8 MB

  convert_x_kernel<<<(MTOT*HIDDEN)/1024, 256, 0, stream>>>(x, xb);
  transpose_w_kernel<<<dim3(32, 32, 4), 256, 0, stream>>>(Wq, Wk, Wv, Wo, wtqkv, wto);
  gemm_bt<1,128><<<dim3(32, 24), 256, 0, stream>>>(xb, wtqkv, bq, bk, bv, qkvb, vtb, nullptr, MTOT, 3*HIDDEN, HIDDEN);
  attn_kernel<<<dim3(SEQ/128, BATCH*NH), 256, 0, stream>>>(qkvb, vtb, aob);
  gemm_bt<0,64><<<dim3(64, 8), 256, 0, stream>>>(aob, wto, bo, nullptr, nullptr, nullptr, nullptr, out, MTOT, HIDDEN, HIDDEN);
}

// Round 6
// 137.899 us; speedup vs baseline: 1.4753x; 1.2901x over previous
//
#include <hip/hip_runtime.h>
#include <hip/hip_bf16.h>

typedef unsigned short u16;
typedef __bf16 bf16x8 __attribute__((ext_vector_type(8)));
typedef float f32x4 __attribute__((ext_vector_type(4)));
typedef float f32x16 __attribute__((ext_vector_type(16)));
typedef unsigned u32x2 __attribute__((ext_vector_type(2)));
typedef unsigned u32x4 __attribute__((ext_vector_type(4)));

#define HIDDEN 1024
#define NH 16
#define HD 64
#define BATCH 2
#define SEQ 2048
#define MTOT (BATCH*SEQ)   // 4096
#define CEXP 0.18033688f   // 0.125 * log2(e), folded into Q at projection time

#if __has_builtin(__builtin_amdgcn_exp2f)
#define EXP2(x) __builtin_amdgcn_exp2f(x)
#else
#define EXP2(x) __builtin_exp2f(x)
#endif

__device__ __forceinline__ u16 f2bf(float f) {
  union { float f; unsigned u; } v; v.f = f;
  unsigned u = v.u;
  return (u16)((u + 0x7fffu + ((u >> 16) & 1u)) >> 16);   // RNE
}

__device__ __forceinline__ unsigned pack2bf(float a, float b) {
  __hip_bfloat162 h = __float22bfloat162_rn(make_float2(a, b));
  unsigned u; __builtin_memcpy(&u, &h, 4); return u;
}

__device__ __forceinline__ void gload16(const u16* g, u16* l) {
  __builtin_amdgcn_global_load_lds((const __attribute__((address_space(1))) unsigned int*)g,
                                   (__attribute__((address_space(3))) unsigned int*)l, 16, 0, 0);
}

// ---------------- prep: x fp32 -> bf16 ----------------
__global__ __launch_bounds__(256) void convert_x_kernel(const float* __restrict__ x,
                                                        u16* __restrict__ xb) {
  size_t i = ((size_t)blockIdx.x * 256 + threadIdx.x) * 4;
  float4 v = *(const float4*)(x + i);
  uint2 p;
  p.x = pack2bf(v.x, v.y);
  p.y = pack2bf(v.z, v.w);
  *(uint2*)(xb + i) = p;
}

// ---------------- prep: W (k,n) fp32 -> Wt (n,k) bf16 ----------------
__global__ __launch_bounds__(256) void transpose_w_kernel(const float* __restrict__ w0, const float* __restrict__ w1,
                                                          const float* __restrict__ w2, const float* __restrict__ w3,
                                                          u16* __restrict__ dqkv, u16* __restrict__ dwo) {
  __shared__ float t[32][33];
  int z = blockIdx.z;
  const float* src = (z==0) ? w0 : (z==1) ? w1 : (z==2) ? w2 : w3;
  u16* dst = (z < 3) ? (dqkv + (size_t)z * HIDDEN * HIDDEN) : dwo;
  int kb = blockIdx.x * 32, nb = blockIdx.y * 32;
  int tx = threadIdx.x & 31, ty = threadIdx.x >> 5;
  for (int r = ty; r < 32; r += 8) t[r][tx] = src[(size_t)(kb + r) * HIDDEN + nb + tx];
  __syncthreads();
  for (int r = ty; r < 32; r += 8) dst[(size_t)(nb + r) * HIDDEN + kb + tx] = f2bf(t[tx][r]);
}

// ---------------- bf16 GEMM: C[m,n] = sum_k A[m,k]*Bt[n,k] + bias ----------------
// MT x 128 tile (MT=128 or 64), BK=32, global_load_lds width-16 staging.
// MODE 0: fp32 out = acc + b0[n]                       (output projection)
// MODE 1: bf16 out, 3 segments: Q (scaled by CEXP) -> Cq, K -> Cq,
//         V -> written TRANSPOSED per head into Cv[(bh*64+d)*SEQ + t]
template<int MODE, int MT>
__global__ __launch_bounds__(256) void gemm_bt(const u16* __restrict__ A, const u16* __restrict__ Bt,
                                               const float* __restrict__ b0, const float* __restrict__ b1,
                                               const float* __restrict__ b2,
                                               u16* __restrict__ Cq, u16* __restrict__ Cv,
                                               float* __restrict__ Cf,
                                               int M, int N, int K) {
  constexpr int MF = MT / 32;           // m-frags per wave: 4 (MT=128) or 2 (MT=64)
  __shared__ u16 As[MT*32];
  __shared__ u16 Bs[128*32];
  const int tid = threadIdx.x, lane = tid & 63, wv = tid >> 6;
  const int m0 = blockIdx.x * MT, n0 = blockIdx.y * 128;
  const int wm = (wv >> 1) * (MT/2), wn = (wv & 1) * 64;
  const int col = lane & 15, quad = lane >> 4;
  const int lr = lane >> 2, lk = (lane & 3) * 8;
  f32x4 acc[MF][4] = {};
  for (int k0 = 0; k0 < K; k0 += 32) {
    if constexpr (MT == 128) {
      gload16(&A[(size_t)(m0 + wv*32      + lr)*K + k0 + lk], &As[wv*1024]);
      gload16(&A[(size_t)(m0 + wv*32 + 16 + lr)*K + k0 + lk], &As[wv*1024 + 512]);
    } else {
      gload16(&A[(size_t)(m0 + wv*16      + lr)*K + k0 + lk], &As[wv*512]);
    }
    gload16(&Bt[(size_t)(n0 + wv*32      + lr)*K + k0 + lk], &Bs[wv*1024]);
    gload16(&Bt[(size_t)(n0 + wv*32 + 16 + lr)*K + k0 + lk], &Bs[wv*1024 + 512]);
    __syncthreads();
    bf16x8 af[MF], bfr[4];
    #pragma unroll
    for (int i = 0; i < MF; i++) af[i]  = *(const bf16x8*)&As[(wm + i*16 + col)*32 + quad*8];
    #pragma unroll
    for (int i = 0; i < 4; i++)  bfr[i] = *(const bf16x8*)&Bs[(wn + i*16 + col)*32 + quad*8];
    #pragma unroll
    for (int mi = 0; mi < MF; mi++)
      #pragma unroll
      for (int ni = 0; ni < 4; ni++)
        acc[mi][ni] = __builtin_amdgcn_mfma_f32_16x16x32_bf16(af[mi], bfr[ni], acc[mi][ni], 0, 0, 0);
    __syncthreads();
  }
  if constexpr (MODE == 0) {
    #pragma unroll
    for (int mi = 0; mi < MF; mi++)
      #pragma unroll
      for (int ni = 0; ni < 4; ni++) {
        int n = n0 + wn + ni*16 + col;
        float bias = b0[n];
        #pragma unroll
        for (int r = 0; r < 4; r++) {
          int m = m0 + wm + mi*16 + quad*4 + r;   // C/D: row = quad*4+reg, col = lane&15
          Cf[(size_t)m*N + n] = acc[mi][ni][r] + bias;
        }
      }
  } else {
    const int seg = n0 >> 10;   // 0=Q, 1=K, 2=V
    if (seg < 2) {
      const float* bias = (seg == 0) ? b0 : b1;
      const float scl = (seg == 0) ? CEXP : 1.0f;
      #pragma unroll
      for (int mi = 0; mi < MF; mi++)
        #pragma unroll
        for (int ni = 0; ni < 4; ni++) {
          int n = n0 + wn + ni*16 + col;
          float bv = bias[n & (HIDDEN-1)];
          #pragma unroll
          for (int r = 0; r < 4; r++) {
            int m = m0 + wm + mi*16 + quad*4 + r;
            Cq[(size_t)m*N + n] = f2bf((acc[mi][ni][r] + bv) * scl);
          }
        }
    } else {
      // V segment: transpose-on-store. n -> (h,d); m -> (b,t); vt[(b*16+h)*64+d][t]
      const int bb = m0 >> 11;             // 2048 % 128 == 0: block never straddles b
      #pragma unroll
      for (int mi = 0; mi < MF; mi++)
        #pragma unroll
        for (int ni = 0; ni < 4; ni++) {
          int local = (n0 + wn + ni*16 + col) & (HIDDEN-1);
          int hh = local >> 6, dd = local & 63;
          float bv = b2[local];
          int t4 = (m0 + wm + mi*16 + quad*4) & (SEQ-1);
          uint2 w2;
          w2.x = pack2bf(acc[mi][ni][0] + bv, acc[mi][ni][1] + bv);
          w2.y = pack2bf(acc[mi][ni][2] + bv, acc[mi][ni][3] + bv);
          *(uint2*)&Cv[((size_t)((bb*NH + hh)*HD + dd))*SEQ + t4] = w2;
        }
    }
  }
}

// ---------------- flash attention: in-block split-K, 8 waves ----------------
// Block = 512 threads, 128 q of one (b,h). Waves 0-3: q-subtile (wv&3) over
// t in [0,1024); waves 4-7: SAME q rows over t in [1024,2048). Each half runs
// the proven 32x32 in-register-P pipeline, 32 t/iter, 32 ITERS (= 1024 t --
// R4's failure was it<16: half the keys dropped, absmax 3.2e-2 from
// subset-averaged softmax). Doubles waves/SIMD (2 -> 4) vs R1 without the
// KVB=128 register blow-up. Partials combined in-LDS at the end: upper waves
// write O (f32, [j][lane]: 2 lanes/bank, conflict-free) + row-sums; lower
// waves add, normalize, store. No extra HBM traffic, no combine kernel.
__global__ __launch_bounds__(512, 4) void attn_kernel(const u16* __restrict__ qkv,
                                                      const u16* __restrict__ vt,
                                                      u16* __restrict__ ao) {
  // K: 2 halves x 2 bufs x [32 t][72] = 18432 B (stride 72: proven R1 pattern)
  // V: 2 halves x 2 bufs x [64 d][40] = 20480 B (stride 40 = 80 B: 16B-aligned
  //    rows, 16B reads spread uniformly over all 32 banks)
  __shared__ u16 SH[19456];   // 38912 B; also reused as f32 combine buffer (33280 B)
  const int tid = threadIdx.x, lane = tid & 63, wv = tid >> 6;
  const int qt = blockIdx.x, bh = blockIdx.y;
  const int b = bh >> 4, h = bh & 15;
  const int l31 = lane & 31, hl = lane >> 5;
  const int qw = wv & 3, half = wv >> 2;
  const int ht = tid & 255;               // thread index within the half-group

  u16* KsH = SH + half*4608;
  u16* VsH = SH + 9216 + half*5120;

  // Q as 32x32x16 B-frags: n=q=l31, elem j at d = kk*16 + hl*8 + j
  bf16x8 qf[4];
  {
    const u16* qrow = qkv + (size_t)(b*SEQ + qt*128 + qw*32 + l31)*(3*HIDDEN) + h*HD + hl*8;
    #pragma unroll
    for (int kk = 0; kk < 4; kk++) qf[kk] = *(const bf16x8*)(qrow + kk*16);
  }

  f32x16 o[2] = {};        // O^T acc [mt]: col=q, rows d = mt*32 + (reg&3)+8*(reg>>2)+4*hl
  float rs0 = 0.f, rs1 = 0.f;

  // K staging (per half): 32 t-rows x 128 B; 8 threads/row
  const int rK = ht >> 3, koK = (ht & 7) * 8;
  // V staging (per half): 64 d-rows x 64 B; 4 threads/row
  const int rV = ht >> 2, koV = (ht & 3) * 8;
  const u16* gK = qkv + (size_t)b*SEQ*(3*HIDDEN) + HIDDEN + (size_t)h*HD;   // row stride 3072
  const u16* gV = vt + (size_t)bh*HD*SEQ;                                    // row stride 2048
  const int tb0 = half * 1024;
  uint4 pK = *(const uint4*)&gK[(size_t)(tb0 + rK)*(3*HIDDEN) + koK];
  uint4 pV = *(const uint4*)&gV[(size_t)rV*SEQ + tb0 + koV];

  for (int it = 0; it < 32; ++it) {      // 32 iters x 32 t = full 1024-t half
    const int curK = (it & 1) * 2304;
    const int curV = (it & 1) * 2560;
    *(uint4*)&KsH[curK + rK*72 + koK] = pK;
    *(uint4*)&VsH[curV + rV*40 + koV] = pV;
    __syncthreads();   // tile visible; other waves at most touch the other buffer
    if (it < 31) {     // prefetch after barrier: loads fly during compute
      int tb = tb0 + (it + 1) * 32;
      pK = *(const uint4*)&gK[(size_t)(tb + rK)*(3*HIDDEN) + koK];
      pV = *(const uint4*)&gV[(size_t)rV*SEQ + tb + koV];
    }

    // S^T = K Q^T: one 32x32 t-subtile, 4 k-steps of 16 over d
    f32x16 s = {};
    __builtin_amdgcn_s_setprio(1);
    #pragma unroll
    for (int kk = 0; kk < 4; kk++) {
      bf16x8 kf = *(const bf16x8*)&KsH[curK + l31*72 + kk*16 + hl*8];
      s = __builtin_amdgcn_mfma_f32_32x32x16_bf16(kf, qf[kk], s, 0, 0, 0);
    }
    __builtin_amdgcn_s_setprio(0);

    // exp2 + rowsum -> packed bf16 -> permlane -> PV fragments
    unsigned w[8];
    #pragma unroll
    for (int j = 0; j < 8; j++) {
      float p0 = EXP2(s[2*j]);
      float p1 = EXP2(s[2*j+1]);
      rs0 += p0; rs1 += p1;
      w[j] = pack2bf(p0, p1);      // t-pair {8*(j>>1)+2*(j&1)+4*hl, +1}
    }
    u32x2 r02 = __builtin_amdgcn_permlane32_swap(w[0], w[2], false, false);
    u32x2 r13 = __builtin_amdgcn_permlane32_swap(w[1], w[3], false, false);
    u32x2 r46 = __builtin_amdgcn_permlane32_swap(w[4], w[6], false, false);
    u32x2 r57 = __builtin_amdgcn_permlane32_swap(w[5], w[7], false, false);
    u32x4 c0, c1;
    c0.x = r02[0]; c0.y = r13[0]; c0.z = r02[1]; c0.w = r13[1];   // t 0..15 of chunk
    c1.x = r46[0]; c1.y = r57[0]; c1.z = r46[1]; c1.w = r57[1];   // t 16..31
    bf16x8 pf0 = __builtin_bit_cast(bf16x8, c0);
    bf16x8 pf1 = __builtin_bit_cast(bf16x8, c1);

    __builtin_amdgcn_s_setprio(1);
    #pragma unroll
    for (int mt = 0; mt < 2; mt++) {
      bf16x8 vf0 = *(const bf16x8*)&VsH[curV + (mt*32 + l31)*40 + hl*8];
      bf16x8 vf1 = *(const bf16x8*)&VsH[curV + (mt*32 + l31)*40 + 16 + hl*8];
      o[mt] = __builtin_amdgcn_mfma_f32_32x32x16_bf16(vf0, pf0, o[mt], 0, 0, 0);
      o[mt] = __builtin_amdgcn_mfma_f32_32x32x16_bf16(vf1, pf1, o[mt], 0, 0, 0);
    }
    __builtin_amdgcn_s_setprio(0);
  }

  // half row-sum for q=l31: own t-subset + half-partner's subset
  float my = rs0 + rs1;
  float fullh = my + __shfl_xor(my, 32, 64);

  // -------- in-LDS split-K combine --------
  __syncthreads();                       // all LDS tile reads done; safe to reuse
  float* cb = (float*)SH;                // 8192 floats O-partials + 128 floats rs
  if (wv >= 4) {
    const int u = wv - 4;
    #pragma unroll
    for (int mt = 0; mt < 2; mt++)
      #pragma unroll
      for (int r = 0; r < 16; r++)
        cb[u*2048 + (mt*16 + r)*64 + lane] = o[mt][r];   // [j][lane]: 2 lanes/bank
    if (hl == 0) cb[8192 + u*32 + l31] = fullh;
  }
  __syncthreads();
  if (wv < 4) {
    #pragma unroll
    for (int mt = 0; mt < 2; mt++)
      #pragma unroll
      for (int r = 0; r < 16; r++)
        o[mt][r] += cb[wv*2048 + (mt*16 + r)*64 + lane];
    float inv = 1.0f / (fullh + cb[8192 + wv*32 + l31]);

    // store O^T -> ao[q][h*64+d]; lane's column q = l31 fixed
    u16* aop = ao + (size_t)(b*SEQ + qt*128 + wv*32 + l31)*HIDDEN + h*HD + hl*4;
    #pragma unroll
    for (int mt = 0; mt < 2; mt++)
      #pragma unroll
      for (int a4 = 0; a4 < 4; a4++) {
        uint2 w2;
        w2.x = pack2bf(o[mt][4*a4+0]*inv, o[mt][4*a4+1]*inv);
        w2.y = pack2bf(o[mt][4*a4+2]*inv, o[mt][4*a4+3]*inv);
        *(uint2*)&aop[mt*32 + 8*a4] = w2;
      }
  }
}

extern "C" void kernel_launch(void* const* d_in, const int* in_sizes, int n_in,
                              void* d_out, int out_size, void* d_ws, size_t ws_size,
                              hipStream_t stream) {
  const float* x  = (const float*)d_in[0];
  const float* Wq = (const float*)d_in[1];
  const float* bq = (const float*)d_in[2];
  const float* Wk = (const float*)d_in[3];
  const float* bk = (const float*)d_in[4];
  const float* Wv = (const float*)d_in[5];
  const float* bv = (const float*)d_in[6];
  const float* Wo = (const float*)d_in[7];
  const float* bo = (const float*)d_in[8];
  float* out = (float*)d_out;

  char* w = (char*)d_ws;
  u16* xb    = (u16*)w; w += (size_t)MTOT*HIDDEN*2;        // 8 MB
  u16* wtqkv = (u16*)w; w += (size_t)3*HIDDEN*HIDDEN*2;    // 6 MB
  u16* wto   = (u16*)w; w += (size_t)HIDDEN*HIDDEN*2;      // 2 MB
  u16* qkvb  = (u16*)w; w += (size_t)MTOT*3*HIDDEN*2;      // 24 MB (V seg unused)
  u16* vtb   = (u16*)w; w += (size_t)BATCH*NH*HD*SEQ*2;    // 8 MB
  u16* aob   = (u16*)w; w += (size_t)MTOT*HIDDEN*2;        // 8 MB

  convert_x_kernel<<<(MTOT*HIDDEN)/1024, 256, 0, stream>>>(x, xb);
  transpose_w_kernel<<<dim3(32, 32, 4), 256, 0, stream>>>(Wq, Wk, Wv, Wo, wtqkv, wto);
  gemm_bt<1,128><<<dim3(32, 24), 256, 0, stream>>>(xb, wtqkv, bq, bk, bv, qkvb, vtb, nullptr, MTOT, 3*HIDDEN, HIDDEN);
  attn_kernel<<<dim3(SEQ/128, BATCH*NH), 512, 0, stream>>>(qkvb, vtb, aob);
  gemm_bt<0,64><<<dim3(64, 8), 256, 0, stream>>>(aob, wto, bo, nullptr, nullptr, nullptr, nullptr, out, MTOT, HIDDEN, HIDDEN);
}

// Round 7
// 133.062 us; speedup vs baseline: 1.5289x; 1.0364x over previous
//
#include <hip/hip_runtime.h>
#include <hip/hip_bf16.h>

typedef unsigned short u16;
typedef __bf16 bf16x8 __attribute__((ext_vector_type(8)));
typedef float f32x4 __attribute__((ext_vector_type(4)));
typedef float f32x16 __attribute__((ext_vector_type(16)));
typedef unsigned u32x2 __attribute__((ext_vector_type(2)));
typedef unsigned u32x4 __attribute__((ext_vector_type(4)));

#define HIDDEN 1024
#define NH 16
#define HD 64
#define BATCH 2
#define SEQ 2048
#define MTOT (BATCH*SEQ)   // 4096
#define CEXP 0.18033688f   // 0.125 * log2(e), folded into Q at projection time

#if __has_builtin(__builtin_amdgcn_exp2f)
#define EXP2(x) __builtin_amdgcn_exp2f(x)
#else
#define EXP2(x) __builtin_exp2f(x)
#endif

__device__ __forceinline__ u16 f2bf(float f) {
  union { float f; unsigned u; } v; v.f = f;
  unsigned u = v.u;
  return (u16)((u + 0x7fffu + ((u >> 16) & 1u)) >> 16);   // RNE
}

__device__ __forceinline__ unsigned pack2bf(float a, float b) {
  __hip_bfloat162 h = __float22bfloat162_rn(make_float2(a, b));
  unsigned u; __builtin_memcpy(&u, &h, 4); return u;
}

__device__ __forceinline__ void gload16(const u16* g, u16* l) {
  __builtin_amdgcn_global_load_lds((const __attribute__((address_space(1))) unsigned int*)g,
                                   (__attribute__((address_space(3))) unsigned int*)l, 16, 0, 0);
}

// ---------------- prep: x fp32 -> bf16 ----------------
__global__ __launch_bounds__(256) void convert_x_kernel(const float* __restrict__ x,
                                                        u16* __restrict__ xb) {
  size_t i = ((size_t)blockIdx.x * 256 + threadIdx.x) * 4;
  float4 v = *(const float4*)(x + i);
  uint2 p;
  p.x = pack2bf(v.x, v.y);
  p.y = pack2bf(v.z, v.w);
  *(uint2*)(xb + i) = p;
}

// ---------------- prep: W (k,n) fp32 -> Wt (n,k) bf16 ----------------
__global__ __launch_bounds__(256) void transpose_w_kernel(const float* __restrict__ w0, const float* __restrict__ w1,
                                                          const float* __restrict__ w2, const float* __restrict__ w3,
                                                          u16* __restrict__ dqkv, u16* __restrict__ dwo) {
  __shared__ float t[32][33];
  int z = blockIdx.z;
  const float* src = (z==0) ? w0 : (z==1) ? w1 : (z==2) ? w2 : w3;
  u16* dst = (z < 3) ? (dqkv + (size_t)z * HIDDEN * HIDDEN) : dwo;
  int kb = blockIdx.x * 32, nb = blockIdx.y * 32;
  int tx = threadIdx.x & 31, ty = threadIdx.x >> 5;
  for (int r = ty; r < 32; r += 8) t[r][tx] = src[(size_t)(kb + r) * HIDDEN + nb + tx];
  __syncthreads();
  for (int r = ty; r < 32; r += 8) dst[(size_t)(nb + r) * HIDDEN + kb + tx] = f2bf(t[tx][r]);
}

// ---------------- bf16 GEMM: C[m,n] = sum_k A[m,k]*Bt[n,k] + bias ----------------
// MT x 128 tile (MT=128 or 64), BK=32, global_load_lds width-16 staging.
// T3-minimum 2-phase pipeline: double-buffered LDS; stage tile k+1 into buf^1
// BEFORE computing tile k; ONE __syncthreads() per iter (drains next-tile loads
// AFTER they've flown under the current tile's ds_read+MFMA). R6 counters showed
// the 1-phase version stall-bound: MfmaUtil 16%, drain uncovered at 32 k-iters.
// MODE 0: fp32 out = acc + b0[n]                       (output projection)
// MODE 1: bf16 out, 3 segments: Q (scaled by CEXP) -> Cq, K -> Cq,
//         V -> written TRANSPOSED per head into Cv[(bh*64+d)*SEQ + t]
template<int MODE, int MT>
__global__ __launch_bounds__(256) void gemm_bt(const u16* __restrict__ A, const u16* __restrict__ Bt,
                                               const float* __restrict__ b0, const float* __restrict__ b1,
                                               const float* __restrict__ b2,
                                               u16* __restrict__ Cq, u16* __restrict__ Cv,
                                               float* __restrict__ Cf,
                                               int M, int N, int K) {
  constexpr int MF = MT / 32;           // m-frags per wave: 4 (MT=128) or 2 (MT=64)
  __shared__ u16 As[2][MT*32];
  __shared__ u16 Bs[2][128*32];
  const int tid = threadIdx.x, lane = tid & 63, wv = tid >> 6;
  const int m0 = blockIdx.x * MT, n0 = blockIdx.y * 128;
  const int wm = (wv >> 1) * (MT/2), wn = (wv & 1) * 64;
  const int col = lane & 15, quad = lane >> 4;
  const int lr = lane >> 2, lk = (lane & 3) * 8;

  auto stage = [&](int kk0, int b) {
    if constexpr (MT == 128) {
      gload16(&A[(size_t)(m0 + wv*32      + lr)*K + kk0 + lk], &As[b][wv*1024]);
      gload16(&A[(size_t)(m0 + wv*32 + 16 + lr)*K + kk0 + lk], &As[b][wv*1024 + 512]);
    } else {
      gload16(&A[(size_t)(m0 + wv*16      + lr)*K + kk0 + lk], &As[b][wv*512]);
    }
    gload16(&Bt[(size_t)(n0 + wv*32      + lr)*K + kk0 + lk], &Bs[b][wv*1024]);
    gload16(&Bt[(size_t)(n0 + wv*32 + 16 + lr)*K + kk0 + lk], &Bs[b][wv*1024 + 512]);
  };

  f32x4 acc[MF][4] = {};
  stage(0, 0);
  __syncthreads();
  int buf = 0;
  for (int k0 = 0; k0 < K; k0 += 32) {
    if (k0 + 32 < K) stage(k0 + 32, buf ^ 1);   // loads fly during this tile's compute
    bf16x8 af[MF], bfr[4];
    #pragma unroll
    for (int i = 0; i < MF; i++) af[i]  = *(const bf16x8*)&As[buf][(wm + i*16 + col)*32 + quad*8];
    #pragma unroll
    for (int i = 0; i < 4; i++)  bfr[i] = *(const bf16x8*)&Bs[buf][(wn + i*16 + col)*32 + quad*8];
    #pragma unroll
    for (int mi = 0; mi < MF; mi++)
      #pragma unroll
      for (int ni = 0; ni < 4; ni++)
        acc[mi][ni] = __builtin_amdgcn_mfma_f32_16x16x32_bf16(af[mi], bfr[ni], acc[mi][ni], 0, 0, 0);
    __syncthreads();   // next-tile loads drained; everyone done reading buf
    buf ^= 1;
  }
  if constexpr (MODE == 0) {
    #pragma unroll
    for (int mi = 0; mi < MF; mi++)
      #pragma unroll
      for (int ni = 0; ni < 4; ni++) {
        int n = n0 + wn + ni*16 + col;
        float bias = b0[n];
        #pragma unroll
        for (int r = 0; r < 4; r++) {
          int m = m0 + wm + mi*16 + quad*4 + r;   // C/D: row = quad*4+reg, col = lane&15
          Cf[(size_t)m*N + n] = acc[mi][ni][r] + bias;
        }
      }
  } else {
    const int seg = n0 >> 10;   // 0=Q, 1=K, 2=V
    if (seg < 2) {
      const float* bias = (seg == 0) ? b0 : b1;
      const float scl = (seg == 0) ? CEXP : 1.0f;
      #pragma unroll
      for (int mi = 0; mi < MF; mi++)
        #pragma unroll
        for (int ni = 0; ni < 4; ni++) {
          int n = n0 + wn + ni*16 + col;
          float bv = bias[n & (HIDDEN-1)];
          #pragma unroll
          for (int r = 0; r < 4; r++) {
            int m = m0 + wm + mi*16 + quad*4 + r;
            Cq[(size_t)m*N + n] = f2bf((acc[mi][ni][r] + bv) * scl);
          }
        }
    } else {
      // V segment: transpose-on-store. n -> (h,d); m -> (b,t); vt[(b*16+h)*64+d][t]
      const int bb = m0 >> 11;             // 2048 % 128 == 0: block never straddles b
      #pragma unroll
      for (int mi = 0; mi < MF; mi++)
        #pragma unroll
        for (int ni = 0; ni < 4; ni++) {
          int local = (n0 + wn + ni*16 + col) & (HIDDEN-1);
          int hh = local >> 6, dd = local & 63;
          float bv = b2[local];
          int t4 = (m0 + wm + mi*16 + quad*4) & (SEQ-1);
          uint2 w2;
          w2.x = pack2bf(acc[mi][ni][0] + bv, acc[mi][ni][1] + bv);
          w2.y = pack2bf(acc[mi][ni][2] + bv, acc[mi][ni][3] + bv);
          *(uint2*)&Cv[((size_t)((bb*NH + hh)*HD + dd))*SEQ + t4] = w2;
        }
    }
  }
}

// ---------------- flash attention: in-block split-K, 8 waves ----------------
// Block = 512 threads, 128 q of one (b,h). Waves 0-3: q-subtile (wv&3) over
// t in [0,1024); waves 4-7: SAME q rows over t in [1024,2048). Each half runs
// the proven 32x32 in-register-P pipeline, 32 t/iter, 32 iters. Partials
// combined in-LDS at the end. (Verified passing in R6.)
__global__ __launch_bounds__(512, 4) void attn_kernel(const u16* __restrict__ qkv,
                                                      const u16* __restrict__ vt,
                                                      u16* __restrict__ ao) {
  // K: 2 halves x 2 bufs x [32 t][72] = 18432 B; V: 2 halves x 2 bufs x [64 d][40] = 20480 B
  __shared__ u16 SH[19456];   // 38912 B; also reused as f32 combine buffer (33280 B)
  const int tid = threadIdx.x, lane = tid & 63, wv = tid >> 6;
  const int qt = blockIdx.x, bh = blockIdx.y;
  const int b = bh >> 4, h = bh & 15;
  const int l31 = lane & 31, hl = lane >> 5;
  const int qw = wv & 3, half = wv >> 2;
  const int ht = tid & 255;               // thread index within the half-group

  u16* KsH = SH + half*4608;
  u16* VsH = SH + 9216 + half*5120;

  // Q as 32x32x16 B-frags: n=q=l31, elem j at d = kk*16 + hl*8 + j
  bf16x8 qf[4];
  {
    const u16* qrow = qkv + (size_t)(b*SEQ + qt*128 + qw*32 + l31)*(3*HIDDEN) + h*HD + hl*8;
    #pragma unroll
    for (int kk = 0; kk < 4; kk++) qf[kk] = *(const bf16x8*)(qrow + kk*16);
  }

  f32x16 o[2] = {};        // O^T acc [mt]: col=q, rows d = mt*32 + (reg&3)+8*(reg>>2)+4*hl
  float rs0 = 0.f, rs1 = 0.f;

  // K staging (per half): 32 t-rows x 128 B; 8 threads/row
  const int rK = ht >> 3, koK = (ht & 7) * 8;
  // V staging (per half): 64 d-rows x 64 B; 4 threads/row
  const int rV = ht >> 2, koV = (ht & 3) * 8;
  const u16* gK = qkv + (size_t)b*SEQ*(3*HIDDEN) + HIDDEN + (size_t)h*HD;   // row stride 3072
  const u16* gV = vt + (size_t)bh*HD*SEQ;                                    // row stride 2048
  const int tb0 = half * 1024;
  uint4 pK = *(const uint4*)&gK[(size_t)(tb0 + rK)*(3*HIDDEN) + koK];
  uint4 pV = *(const uint4*)&gV[(size_t)rV*SEQ + tb0 + koV];

  for (int it = 0; it < 32; ++it) {      // 32 iters x 32 t = full 1024-t half
    const int curK = (it & 1) * 2304;
    const int curV = (it & 1) * 2560;
    *(uint4*)&KsH[curK + rK*72 + koK] = pK;
    *(uint4*)&VsH[curV + rV*40 + koV] = pV;
    __syncthreads();   // tile visible; other waves at most touch the other buffer
    if (it < 31) {     // prefetch after barrier: loads fly during compute
      int tb = tb0 + (it + 1) * 32;
      pK = *(const uint4*)&gK[(size_t)(tb + rK)*(3*HIDDEN) + koK];
      pV = *(const uint4*)&gV[(size_t)rV*SEQ + tb + koV];
    }

    // S^T = K Q^T: one 32x32 t-subtile, 4 k-steps of 16 over d
    f32x16 s = {};
    __builtin_amdgcn_s_setprio(1);
    #pragma unroll
    for (int kk = 0; kk < 4; kk++) {
      bf16x8 kf = *(const bf16x8*)&KsH[curK + l31*72 + kk*16 + hl*8];
      s = __builtin_amdgcn_mfma_f32_32x32x16_bf16(kf, qf[kk], s, 0, 0, 0);
    }
    __builtin_amdgcn_s_setprio(0);

    // exp2 + rowsum -> packed bf16 -> permlane -> PV fragments
    unsigned w[8];
    #pragma unroll
    for (int j = 0; j < 8; j++) {
      float p0 = EXP2(s[2*j]);
      float p1 = EXP2(s[2*j+1]);
      rs0 += p0; rs1 += p1;
      w[j] = pack2bf(p0, p1);      // t-pair {8*(j>>1)+2*(j&1)+4*hl, +1}
    }
    u32x2 r02 = __builtin_amdgcn_permlane32_swap(w[0], w[2], false, false);
    u32x2 r13 = __builtin_amdgcn_permlane32_swap(w[1], w[3], false, false);
    u32x2 r46 = __builtin_amdgcn_permlane32_swap(w[4], w[6], false, false);
    u32x2 r57 = __builtin_amdgcn_permlane32_swap(w[5], w[7], false, false);
    u32x4 c0, c1;
    c0.x = r02[0]; c0.y = r13[0]; c0.z = r02[1]; c0.w = r13[1];   // t 0..15 of chunk
    c1.x = r46[0]; c1.y = r57[0]; c1.z = r46[1]; c1.w = r57[1];   // t 16..31
    bf16x8 pf0 = __builtin_bit_cast(bf16x8, c0);
    bf16x8 pf1 = __builtin_bit_cast(bf16x8, c1);

    __builtin_amdgcn_s_setprio(1);
    #pragma unroll
    for (int mt = 0; mt < 2; mt++) {
      bf16x8 vf0 = *(const bf16x8*)&VsH[curV + (mt*32 + l31)*40 + hl*8];
      bf16x8 vf1 = *(const bf16x8*)&VsH[curV + (mt*32 + l31)*40 + 16 + hl*8];
      o[mt] = __builtin_amdgcn_mfma_f32_32x32x16_bf16(vf0, pf0, o[mt], 0, 0, 0);
      o[mt] = __builtin_amdgcn_mfma_f32_32x32x16_bf16(vf1, pf1, o[mt], 0, 0, 0);
    }
    __builtin_amdgcn_s_setprio(0);
  }

  // half row-sum for q=l31: own t-subset + half-partner's subset
  float my = rs0 + rs1;
  float fullh = my + __shfl_xor(my, 32, 64);

  // -------- in-LDS split-K combine --------
  __syncthreads();                       // all LDS tile reads done; safe to reuse
  float* cb = (float*)SH;                // 8192 floats O-partials + 128 floats rs
  if (wv >= 4) {
    const int u = wv - 4;
    #pragma unroll
    for (int mt = 0; mt < 2; mt++)
      #pragma unroll
      for (int r = 0; r < 16; r++)
        cb[u*2048 + (mt*16 + r)*64 + lane] = o[mt][r];   // [j][lane]: 2 lanes/bank
    if (hl == 0) cb[8192 + u*32 + l31] = fullh;
  }
  __syncthreads();
  if (wv < 4) {
    #pragma unroll
    for (int mt = 0; mt < 2; mt++)
      #pragma unroll
      for (int r = 0; r < 16; r++)
        o[mt][r] += cb[wv*2048 + (mt*16 + r)*64 + lane];
    float inv = 1.0f / (fullh + cb[8192 + wv*32 + l31]);

    // store O^T -> ao[q][h*64+d]; lane's column q = l31 fixed
    u16* aop = ao + (size_t)(b*SEQ + qt*128 + wv*32 + l31)*HIDDEN + h*HD + hl*4;
    #pragma unroll
    for (int mt = 0; mt < 2; mt++)
      #pragma unroll
      for (int a4 = 0; a4 < 4; a4++) {
        uint2 w2;
        w2.x = pack2bf(o[mt][4*a4+0]*inv, o[mt][4*a4+1]*inv);
        w2.y = pack2bf(o[mt][4*a4+2]*inv, o[mt][4*a4+3]*inv);
        *(uint2*)&aop[mt*32 + 8*a4] = w2;
      }
  }
}

extern "C" void kernel_launch(void* const* d_in, const int* in_sizes, int n_in,
                              void* d_out, int out_size, void* d_ws, size_t ws_size,
                              hipStream_t stream) {
  const float* x  = (const float*)d_in[0];
  const float* Wq = (const float*)d_in[1];
  const float* bq = (const float*)d_in[2];
  const float* Wk = (const float*)d_in[3];
  const float* bk = (const float*)d_in[4];
  const float* Wv = (const float*)d_in[5];
  const float* bv = (const float*)d_in[6];
  const float* Wo = (const float*)d_in[7];
  const float* bo = (const float*)d_in[8];
  float* out = (float*)d_out;

  char* w = (char*)d_ws;
  u16* xb    = (u16*)w; w += (size_t)MTOT*HIDDEN*2;        // 8 MB
  u16* wtqkv = (u16*)w; w += (size_t)3*HIDDEN*HIDDEN*2;    // 6 MB
  u16* wto   = (u16*)w; w += (size_t)HIDDEN*HIDDEN*2;      // 2 MB
  u16* qkvb  = (u16*)w; w += (size_t)MTOT*3*HIDDEN*2;      // 24 MB (V seg unused)
  u16* vtb   = (u16*)w; w += (size_t)BATCH*NH*HD*SEQ*2;    // 8 MB
  u16* aob   = (u16*)w; w += (size_t)MTOT*HIDDEN*2;        // 8 MB

  convert_x_kernel<<<(MTOT*HIDDEN)/1024, 256, 0, stream>>>(x, xb);
  transpose_w_kernel<<<dim3(32, 32, 4), 256, 0, stream>>>(Wq, Wk, Wv, Wo, wtqkv, wto);
  gemm_bt<1,128><<<dim3(32, 24), 256, 0, stream>>>(xb, wtqkv, bq, bk, bv, qkvb, vtb, nullptr, MTOT, 3*HIDDEN, HIDDEN);
  attn_kernel<<<dim3(SEQ/128, BATCH*NH), 512, 0, stream>>>(qkvb, vtb, aob);
  gemm_bt<0,64><<<dim3(64, 8), 256, 0, stream>>>(aob, wto, bo, nullptr, nullptr, nullptr, nullptr, out, MTOT, HIDDEN, HIDDEN);
}